// Round 21
// baseline (295.893 us; speedup 1.0000x reference)
//
#include <hip/hip_runtime.h>
#include <math.h>

#define Nn 512
#define Mm 32000
#define Bb 64
#define Tt 256
#define NCONS 4     // consumer (recursion) blocks, 512 threads / 8 waves each
#define NPROD 128   // producer (emission gather) blocks

typedef float v4f __attribute__((ext_vector_type(4)));
typedef float f4  __attribute__((ext_vector_type(4)));
typedef int   v4i __attribute__((ext_vector_type(4)));
typedef int   v8i __attribute__((ext_vector_type(8)));

// pack 4 f32 -> 4 OCP e4m3 bytes in an int
__device__ inline int pk4fp8(float a, float b, float c, float d) {
  int r = __builtin_amdgcn_cvt_pk_fp8_f32(a, b, 0, false);
  r = __builtin_amdgcn_cvt_pk_fp8_f32(c, d, r, true);
  return r;
}

// ---- prelude: rowsum[j] = sum_m exp(emis[j][m]) (512 blocks, 1 row each) and
// ---- colsum[k] = sum_j exp(trans[j][k]) (32 stripe blocks) — full-device, HBM-bound
__global__ void k_pre(const float* __restrict__ trans, const float* __restrict__ emis,
                      float* __restrict__ colsum, float* __restrict__ rowsum) {
  __shared__ float ss[256];
  const int tid = threadIdx.x, bid = blockIdx.x;
  if (bid < 512) {
    const f4* row4 = (const f4*)(emis + (size_t)bid * Mm);
    float s = 0.f;
    for (int i = tid; i < Mm / 4; i += 256) {
      f4 v = row4[i];
      s += (__expf(v[0]) + __expf(v[1])) + (__expf(v[2]) + __expf(v[3]));
    }
    ss[tid] = s; __syncthreads();
    for (int off = 128; off; off >>= 1) { if (tid < off) ss[tid] += ss[tid + off]; __syncthreads(); }
    if (tid == 0) rowsum[bid] = ss[0];
  } else {
    int j0 = (bid - 512) * 16;
    float a0 = 0.f, a1 = 0.f;
    for (int r = 0; r < 16; ++r) {
      a0 += __expf(trans[(j0 + r) * Nn + tid]);
      a1 += __expf(trans[(j0 + r) * Nn + 256 + tid]);
    }
    atomicAdd(&colsum[tid], a0);
    atomicAdd(&colsum[256 + tid], a1);
  }
}

// ---- A'[j][k] = 2^23 * exp(trans[j][k]) / (colsum[k] * rowsum[j]) as e4m3
// ---- (rowsum folded into A rows: pem becomes RAW exp(emis), no producer scan).
// ---- Block 256: pi2[j] = 2^23 * exp(prior[j]) / (ptot * rowsum[j]) for t=0 init.
__global__ void k_writeA8(const float* __restrict__ trans, const float* __restrict__ colsum,
                          const float* __restrict__ rowsum, const float* __restrict__ prior,
                          int* __restrict__ A8, float* __restrict__ pi2) {
  const int tid = threadIdx.x;
  if (blockIdx.x == 256) {
    __shared__ float ss[256];
    float e0 = __expf(prior[tid]), e1 = __expf(prior[tid + 256]);
    ss[tid] = e0 + e1; __syncthreads();
    for (int off = 128; off; off >>= 1) { if (tid < off) ss[tid] += ss[tid + off]; __syncthreads(); }
    float ptot = ss[0];
    pi2[tid]       = 8388608.f * e0 / (ptot * rowsum[tid]);
    pi2[tid + 256] = 8388608.f * e1 / (ptot * rowsum[tid + 256]);
    return;
  }
  int d = blockIdx.x * 256 + tid;
  int j = d >> 7, k0 = (d & 127) << 2;
  float f = 8388608.f / rowsum[j];           // 2^23 / rowsum[j]
  float v0 = f * __expf(trans[j * Nn + k0 + 0]) / colsum[k0 + 0];
  float v1 = f * __expf(trans[j * Nn + k0 + 1]) / colsum[k0 + 1];
  float v2 = f * __expf(trans[j * Nn + k0 + 2]) / colsum[k0 + 2];
  float v3 = f * __expf(trans[j * Nn + k0 + 3]) / colsum[k0 + 3];
  A8[d] = pk4fp8(v0, v1, v2, v3);
}

// ---- fused: blocks 0-3 recursion consumers (8 waves, 64 A-rows/wave),
// ---- blocks 4-131 producers = PURE GATHER (rowsum folded into A8, so Pem2 = raw
// ---- exp(emis[j, x[b,t]]) — no scan, no reductions; chunk 0 publishes ~3us in).
__global__ __attribute__((amdgpu_flat_work_group_size(512, 512), amdgpu_waves_per_eu(2, 2)))
void k_fused(
    const char* __restrict__ A8, const float* __restrict__ emis,
    const int* __restrict__ x, const float* __restrict__ pi2,
    const int* __restrict__ Tlen, float* __restrict__ Pem2,
    int* __restrict__ progress, float* __restrict__ out)
{
  __shared__ __align__(16) char ybuf[2][16 * Nn];   // fp8 Y [c][k], XOR-swizzled; 16 KB
  const int tid = threadIdx.x;

  if (blockIdx.x >= NCONS) {
    // ================= producer: gather 4 rows, publish in 32-t chunks =================
    const int p = blockIdx.x - NCONS;      // j-quad p -> emis rows 4p..4p+3
    const int j0 = p * 4;
    const float* r0 = emis + (size_t)(j0 + 0) * Mm;
    const float* r1 = emis + (size_t)(j0 + 1) * Mm;
    const float* r2 = emis + (size_t)(j0 + 2) * Mm;
    const float* r3 = emis + (size_t)(j0 + 3) * Mm;
    f4* P4 = (f4*)Pem2;
    for (int c8 = 0; c8 < 8; ++c8) {
      #pragma unroll
      for (int r = 0; r < 4; ++r) {
        int idx = c8 * 2048 + r * 512 + tid;
        int t = idx >> 6, b = idx & 63;
        int mv = x[b * Tt + t];
        f4 o = { __expf(r0[mv]), __expf(r1[mv]), __expf(r2[mv]), __expf(r3[mv]) };
        P4[t * 8192 + (b >> 4) * 2048 + p * 16 + (b & 15)] = o;
      }
      __syncthreads();
      if (tid == 0) {
        __builtin_amdgcn_fence(__ATOMIC_RELEASE, "agent");
        __hip_atomic_fetch_add(&progress[c8], 1, __ATOMIC_RELAXED, __HIP_MEMORY_SCOPE_AGENT);
      }
    }
    return;
  }

  // ================= consumer: 8 waves, 64 A-rows each =================
  const int g = blockIdx.x;
  const int w = tid >> 6, lane = tid & 63;
  const int c = lane & 15, kq = lane >> 4;
  const int jw = w * 64;                    // this wave's 64 A-rows
  const int swz = (c & 7) << 4;
  const int b = g * 16 + c;

  // A fragments (one-time): lane holds A'[jw+rt*16+c][kc*128+kq*32 .. +31]  (128 regs)
  v8i af[4][4];
  #pragma unroll
  for (int rt = 0; rt < 4; ++rt)
    #pragma unroll
    for (int kc = 0; kc < 4; ++kc)
      af[rt][kc] = *reinterpret_cast<const v8i*>(
          A8 + (size_t)(jw + rt * 16 + c) * Nn + kc * 128 + kq * 32);

  // ones-A operand: e4m3 1.0 = 0x38 in all 32 bytes
  v8i onesv;
  #pragma unroll
  for (int u = 0; u < 8; ++u) onesv[u] = 0x38383838;

  // launder: block rematerialization/sinking into the loop
  #pragma unroll
  for (int rt = 0; rt < 4; ++rt)
    #pragma unroll
    for (int kc = 0; kc < 4; ++kc)
      asm volatile("" : "+v"(af[rt][kc]));
  asm volatile("" : "+v"(onesv));

  const int Tb = Tlen[b];
  int E = 23;                               // Y = 2^E * alpha
  int csafe = 0;

  #define ENSURE(NEED)                                                                      \
    while (csafe <= (NEED)) {                                                               \
      if (__hip_atomic_load(&progress[csafe], __ATOMIC_RELAXED,                             \
                            __HIP_MEMORY_SCOPE_AGENT) >= NPROD) {                           \
        ++csafe;                                                                            \
        __builtin_amdgcn_fence(__ATOMIC_ACQUIRE, "agent");                                  \
      } else __builtin_amdgcn_s_sleep(2);                                                   \
    }

  // LDS byte offsets. Writes use XOR (wf_rt = wf0 ^ rt*16); reads add kc*128.
  const int roA0 = (c * Nn + kq * 32) ^ swz;
  const int roB0 = roA0 ^ 16;
  const int wf0 = (c * Nn + jw + kq * 4) ^ swz;
  const int wf1 = wf0 ^ 16, wf2 = wf0 ^ 32, wf3 = wf0 ^ 48;
  char* const yb0 = &ybuf[0][0];

  // precomputed loop-invariant bases (odd step: read buf0 -> write buf1)
  const char* rdA_e = yb0 + roA0;          // odd-step read bases (buf0)
  const char* rdB_e = yb0 + roB0;
  const char* rdA_o = rdA_e + 8192;        // even-step read bases (buf1)
  const char* rdB_o = rdB_e + 8192;
  char* const wb_o = yb0 + 8192;           // odd-step write base (buf1)
  char* const wb_e = yb0;                  // even-step write base (buf0)

  ENSURE(0);                                // Pem2 chunk 0 ready

  // init: Y0 = pi2[j] * Pem2raw[0][j][c']  (pi2 carries 2^23 * pi / rowsum)
  {
    int cc = tid & 15, grp = tid >> 4, jb = grp * 16, sz = (cc & 7) << 4;
    const f4* P0 = (const f4*)Pem2 + g * 2048 + (jb >> 2) * 16 + cc;
    const f4* PI = (const f4*)pi2 + (jb >> 2);
    #pragma unroll
    for (int q = 0; q < 4; ++q) {
      f4 v = P0[q * 16] * PI[q];
      *reinterpret_cast<int*>(yb0 + ((cc * Nn + jb + q * 4) ^ sz)) = pk4fp8(v[0], v[1], v[2], v[3]);
    }
  }
  __syncthreads();

  // pem pointer: PIDX(1,0) = 8192 + g*2048 + jw*4 + kq*16 + c (f4 units);
  // RT stride 64 f4 (imm offsets); timestep stride 8192 f4.
  const f4* pemP = (const f4*)Pem2 + (8192 + g * 2048 + jw * 4 + kq * 16 + c);

  union BU { v8i v; v4i h[2]; };

  // ones-chain FIRST in each kc group (as_ completes 4 slots early); 5 independent
  // accumulator chains, dep distance 5.
  #define LOADMFMA(RDA, RDB)                                                                 \
    BU b0, b1, b2, b3;                                                                       \
    b0.h[0] = *(const v4i*)((RDA) + 0);   b0.h[1] = *(const v4i*)((RDB) + 0);                \
    b1.h[0] = *(const v4i*)((RDA) + 128); b1.h[1] = *(const v4i*)((RDB) + 128);              \
    b2.h[0] = *(const v4i*)((RDA) + 256); b2.h[1] = *(const v4i*)((RDB) + 256);              \
    b3.h[0] = *(const v4i*)((RDA) + 384); b3.h[1] = *(const v4i*)((RDB) + 384);              \
    v4f a0 = {0.f,0.f,0.f,0.f}, a1 = {0.f,0.f,0.f,0.f};                                     \
    v4f a2 = {0.f,0.f,0.f,0.f}, a3 = {0.f,0.f,0.f,0.f};                                     \
    v4f as_ = {0.f,0.f,0.f,0.f};                                                            \
    as_ = __builtin_amdgcn_mfma_scale_f32_16x16x128_f8f6f4(onesv,    b0.v, as_, 0,0,0, 0x7F, 0, 0x7F); \
    a0  = __builtin_amdgcn_mfma_scale_f32_16x16x128_f8f6f4(af[0][0], b0.v, a0, 0,0,0, 0x7F, 0, 0x7F); \
    a1  = __builtin_amdgcn_mfma_scale_f32_16x16x128_f8f6f4(af[1][0], b0.v, a1, 0,0,0, 0x7F, 0, 0x7F); \
    a2  = __builtin_amdgcn_mfma_scale_f32_16x16x128_f8f6f4(af[2][0], b0.v, a2, 0,0,0, 0x7F, 0, 0x7F); \
    a3  = __builtin_amdgcn_mfma_scale_f32_16x16x128_f8f6f4(af[3][0], b0.v, a3, 0,0,0, 0x7F, 0, 0x7F); \
    as_ = __builtin_amdgcn_mfma_scale_f32_16x16x128_f8f6f4(onesv,    b1.v, as_, 0,0,0, 0x7F, 0, 0x7F); \
    a0  = __builtin_amdgcn_mfma_scale_f32_16x16x128_f8f6f4(af[0][1], b1.v, a0, 0,0,0, 0x7F, 0, 0x7F); \
    a1  = __builtin_amdgcn_mfma_scale_f32_16x16x128_f8f6f4(af[1][1], b1.v, a1, 0,0,0, 0x7F, 0, 0x7F); \
    a2  = __builtin_amdgcn_mfma_scale_f32_16x16x128_f8f6f4(af[2][1], b1.v, a2, 0,0,0, 0x7F, 0, 0x7F); \
    a3  = __builtin_amdgcn_mfma_scale_f32_16x16x128_f8f6f4(af[3][1], b1.v, a3, 0,0,0, 0x7F, 0, 0x7F); \
    as_ = __builtin_amdgcn_mfma_scale_f32_16x16x128_f8f6f4(onesv,    b2.v, as_, 0,0,0, 0x7F, 0, 0x7F); \
    a0  = __builtin_amdgcn_mfma_scale_f32_16x16x128_f8f6f4(af[0][2], b2.v, a0, 0,0,0, 0x7F, 0, 0x7F); \
    a1  = __builtin_amdgcn_mfma_scale_f32_16x16x128_f8f6f4(af[1][2], b2.v, a1, 0,0,0, 0x7F, 0, 0x7F); \
    a2  = __builtin_amdgcn_mfma_scale_f32_16x16x128_f8f6f4(af[2][2], b2.v, a2, 0,0,0, 0x7F, 0, 0x7F); \
    a3  = __builtin_amdgcn_mfma_scale_f32_16x16x128_f8f6f4(af[3][2], b2.v, a3, 0,0,0, 0x7F, 0, 0x7F); \
    as_ = __builtin_amdgcn_mfma_scale_f32_16x16x128_f8f6f4(onesv,    b3.v, as_, 0,0,0, 0x7F, 0, 0x7F); \
    a0  = __builtin_amdgcn_mfma_scale_f32_16x16x128_f8f6f4(af[0][3], b3.v, a0, 0,0,0, 0x7F, 0, 0x7F); \
    a1  = __builtin_amdgcn_mfma_scale_f32_16x16x128_f8f6f4(af[1][3], b3.v, a1, 0,0,0, 0x7F, 0, 0x7F); \
    a2  = __builtin_amdgcn_mfma_scale_f32_16x16x128_f8f6f4(af[2][3], b3.v, a2, 0,0,0, 0x7F, 0, 0x7F); \
    a3  = __builtin_amdgcn_mfma_scale_f32_16x16x128_f8f6f4(af[3][3], b3.v, a3, 0,0,0, 0x7F, 0, 0x7F);

  #define EPILOG(WBASE)                                                                      \
    {                                                                                        \
      v4f scl4 = {scl, scl, scl, scl};                                                       \
      v4f v0 = a0 * (pem0 * scl4);                                                           \
      v4f v1 = a1 * (pem1 * scl4);                                                           \
      v4f v2 = a2 * (pem2 * scl4);                                                           \
      v4f v3 = a3 * (pem3 * scl4);                                                           \
      *(int*)((WBASE) + wf0) = pk4fp8(v0[0], v0[1], v0[2], v0[3]);                           \
      *(int*)((WBASE) + wf1) = pk4fp8(v1[0], v1[1], v1[2], v1[3]);                           \
      *(int*)((WBASE) + wf2) = pk4fp8(v2[0], v2[1], v2[2], v2[3]);                           \
      *(int*)((WBASE) + wf3) = pk4fp8(v3[0], v3[1], v3[2], v3[3]);                           \
    }

  for (int t = 1; t <= Tt; t += 2) {
    // ---------- ODD step t (t <= 255 < Tt always): read buf0, write buf1 ----------
    {
      f4 pem0 = pemP[0], pem1 = pemP[64], pem2 = pemP[128], pem3 = pemP[192];
      LOADMFMA(rdA_e, rdB_e)
      float S = as_[0];                     // S_c = sum_k Y_{t-1}[k,c], identical all waves
      int expb = (int)((__float_as_uint(S) >> 23) & 0xFF);
      if (w == 0 && kq == 0 && Tb == t) out[b] = __logf(S) - (float)E * 0.69314718056f;
      E += 150 - expb;                      // E += 23 - ilogb(S)
      float scl = __uint_as_float((unsigned)(254 - expb) << 23);   // 2^-ilogb(S)
      EPILOG(wb_o)
      __syncthreads();
    }
    // ---------- EVEN step t+1: read buf1, write buf0 ----------
    {
      const int T = t + 1;
      if (T < Tt && (T & 31) == 0) ENSURE(T >> 5);
      f4 pem0, pem1, pem2, pem3;
      const f4* p2 = pemP + 8192;          // next timestep (8192 f4 stride)
      if (T < Tt) { pem0 = p2[0]; pem1 = p2[64]; pem2 = p2[128]; pem3 = p2[192]; }
      LOADMFMA(rdA_o, rdB_o)
      float S = as_[0];
      int expb = (int)((__float_as_uint(S) >> 23) & 0xFF);
      if (w == 0 && kq == 0 && Tb == T) out[b] = __logf(S) - (float)E * 0.69314718056f;
      if (T == Tt) goto done;
      E += 150 - expb;
      float scl = __uint_as_float((unsigned)(254 - expb) << 23);
      EPILOG(wb_e)
      __syncthreads();
    }
    pemP += 16384;                          // two timesteps
  }
done: ;
  #undef LOADMFMA
  #undef EPILOG
  #undef ENSURE
}

extern "C" void kernel_launch(void* const* d_in, const int* in_sizes, int n_in,
                              void* d_out, int out_size, void* d_ws, size_t ws_size,
                              hipStream_t stream) {
  const int*   x     = (const int*)  d_in[0];
  const int*   Tlen  = (const int*)  d_in[1];
  const float* trans = (const float*)d_in[2];
  const float* emis  = (const float*)d_in[3];
  const float* prior = (const float*)d_in[4];
  float* out = (float*)d_out;

  char* w = (char*)d_ws;
  char*  A8       = (char*)(w);                        // 256 KB fp8 A'[j][k] (rs folded)
  float* colsum   = (float*)(w + (512 << 10));         // 2 KB
  float* rowsum   = (float*)(w + (512 << 10) + 2048);  // 2 KB
  float* pi2      = (float*)(w + (512 << 10) + 4096);  // 2 KB
  int*   progress = (int*)  (w + (512 << 10) + 8192);  // 8 chunk counters
  float* Pem2     = (float*)(w + (1024 << 10));        // 32 MB Pem2raw[t][g][j>>2][c][j&3]

  hipMemsetAsync(w + (512 << 10), 0, 12288, stream);   // colsum+rowsum+pi2+progress
  k_pre    <<<544, 256, 0, stream>>>(trans, emis, colsum, rowsum);
  k_writeA8<<<257, 256, 0, stream>>>(trans, colsum, rowsum, prior, (int*)A8, pi2);
  k_fused  <<<NCONS + NPROD, 512, 0, stream>>>(A8, emis, x, pi2, Tlen, Pem2, progress, out);
}